// Round 5
// baseline (65.230 us; speedup 1.0000x reference)
//
#include <hip/hip_runtime.h>
#include <math.h>

// BioMechFeatures: B x 12 x 256 f32 (foot, shank, thigh) -> B x 44 f32.
// Kernel 1 (build_trig): precompute DFT B-matrix bf16 MFMA fragments -> d_ws (128 KB).
// Kernel 2 (biomech): block = 512 threads (8 waves) = 8 batches, 1 batch/wave.
//   Phase 1: per-wave stats (shuffle reductions), stage foot-z rows bf16 -> swizzled LDS.
//   Phase 2: DFT power via mfma_f32_16x16x32_bf16; B fragments streamed from d_ws (L2-hot).
//   Phase 3: 16 threads combine spectral partials -> hf, sc.

typedef __attribute__((ext_vector_type(8))) short short8;
typedef __attribute__((ext_vector_type(4))) float f32x4;

__device__ __forceinline__ float wsum(float v){
  v += __shfl_xor(v,1); v += __shfl_xor(v,2); v += __shfl_xor(v,4);
  v += __shfl_xor(v,8); v += __shfl_xor(v,16); v += __shfl_xor(v,32);
  return v;
}
__device__ __forceinline__ float wmax(float v){
  v = fmaxf(v,__shfl_xor(v,1)); v = fmaxf(v,__shfl_xor(v,2)); v = fmaxf(v,__shfl_xor(v,4));
  v = fmaxf(v,__shfl_xor(v,8)); v = fmaxf(v,__shfl_xor(v,16)); v = fmaxf(v,__shfl_xor(v,32));
  return v;
}
__device__ __forceinline__ float red16(float v){  // sum across lane&15 group
  v += __shfl_xor(v,1); v += __shfl_xor(v,2); v += __shfl_xor(v,4); v += __shfl_xor(v,8);
  return v;
}
__device__ __forceinline__ float sum4(float4 v){ return (v.x+v.y)+(v.z+v.w); }
__device__ __forceinline__ float dot4(float4 v){ return (v.x*v.x+v.y*v.y)+(v.z*v.z+v.w*v.w); }
__device__ __forceinline__ float amax4(float4 v){ return fmaxf(fmaxf(fabsf(v.x),fabsf(v.y)),fmaxf(fabsf(v.z),fabsf(v.w))); }
__device__ __forceinline__ float asum4(float4 v){ return (fabsf(v.x)+fabsf(v.y))+(fabsf(v.z)+fabsf(v.w)); }
__device__ __forceinline__ float clampf(float v,float lo,float hi){ return fminf(fmaxf(v,lo),hi); }
__device__ __forceinline__ unsigned short f2bf(float f){   // RNE f32->bf16
  unsigned u = __float_as_uint(f);
  return (unsigned short)((u + 0x7FFFu + ((u>>16)&1u)) >> 16);
}

// ---------- B-fragment precompute: 8 tiles x 8 s x {cos,sin} x 64 lanes x 8 bf16 ----------
__global__ __launch_bounds__(256) void build_trig(unsigned short* __restrict__ ws){
  int id   = blockIdx.x*256 + threadIdx.x;   // 0..8191
  int lane = id & 63;
  int f    = (id>>6) & 1;                    // 0=cos, 1=sin
  int s    = (id>>7) & 7;
  int T    = (id>>10) & 7;                   // bin tile
  int nb   = T*16 + (lane&15);               // bin
  int n0   = ((lane>>4)<<3) + (s<<5);        // sample base
  short8 v;
  #pragma unroll
  for (int j=0;j<8;++j){
    int m = ((n0+j)*nb) & 255;
    if (f) m = (m+192)&255;                  // sin(x) = cos(x - pi/2)
    v[j] = (short)f2bf(__cosf((float)m * 0.0245436926066f));
  }
  *(short8*)(ws + (size_t)id*8) = v;
}

__global__ __launch_bounds__(512,4) void biomech_kernel(
    const float* __restrict__ foot, const float* __restrict__ shank,
    const float* __restrict__ thigh, const unsigned short* __restrict__ ws,
    float* __restrict__ out, int B)
{
  const int t    = threadIdx.x;
  const int lane = t & 63;
  const int wv   = t >> 6;                 // 0..7

  __shared__ __align__(16) unsigned short sA[16*256];  // 8KB bf16 A, XOR-swizzled
  __shared__ float sPart[8][16][3];
  __shared__ float sAlt[16];

  const long long b = (long long)blockIdx.x*8 + wv;
  if (b < B) {
    const float* fp = foot  + (size_t)b*3072;
    const float* sp = shank + (size_t)b*3072;
    const float* tp = thigh + (size_t)b*3072;

    // ---- issue z loads + first gyro group early
    float4 xl = ((const float4*)(fp+ 512))[lane];
    float4 xr = ((const float4*)(fp+2048))[lane];
    float4 yl = ((const float4*)(sp+ 512))[lane];
    float4 yr = ((const float4*)(sp+2048))[lane];
    float4 gc0 = ((const float4*)(fp+ 768))[lane];
    float4 gc1 = ((const float4*)(fp+1024))[lane];
    float4 gc2 = ((const float4*)(fp+1280))[lane];

    // ---- stage foot-z rows bf16 into swizzled LDS (rows 2wv, 2wv+1)
    {
      int r0 = 2*wv, r1 = 2*wv+1;
      unsigned lo0 = (unsigned)f2bf(xl.x) | ((unsigned)f2bf(xl.y)<<16);
      unsigned hi0 = (unsigned)f2bf(xl.z) | ((unsigned)f2bf(xl.w)<<16);
      unsigned by0 = (((unsigned)r0<<9) + ((unsigned)lane<<3)) ^ (((unsigned)(r0&7))<<4);
      *(uint2*)((char*)sA + by0) = make_uint2(lo0,hi0);
      unsigned lo1 = (unsigned)f2bf(xr.x) | ((unsigned)f2bf(xr.y)<<16);
      unsigned hi1 = (unsigned)f2bf(xr.z) | ((unsigned)f2bf(xr.w)<<16);
      unsigned by1 = (((unsigned)r1<<9) + ((unsigned)lane<<3)) ^ (((unsigned)(r1&7))<<4);
      *(uint2*)((char*)sA + by1) = make_uint2(lo1,hi1);
    }

    // ---- z-channel reductions
    float pk_l  = wmax(amax4(xl)), pk_r  = wmax(amax4(xr));
    float spk_l = wmax(amax4(yl)), spk_r = wmax(amax4(yr));
    float sum_l = wsum(sum4(xl)),  sum_r = wsum(sum4(xr));
    float sq_l  = wsum(dot4(xl)),  sq_r  = wsum(dot4(xr));
    float ssum_l= wsum(sum4(yl)),  ssum_r= wsum(sum4(yr));
    float ssq_l = wsum(dot4(yl)),  ssq_r = wsum(dot4(yr));
    float al = asum4(xl), ar = asum4(xr);
    float h1l = wsum(lane<32 ? al : 0.f), h2l = wsum(lane<32 ? 0.f : al);
    float h1r = wsum(lane<32 ? ar : 0.f), h2r = wsum(lane<32 ? 0.f : ar);
    float alt_l = wsum((xl.x - xl.y) + (xl.z - xl.w));
    float alt_r = wsum((xr.x - xr.y) + (xr.z - xr.w));
    if (lane == 0) { sAlt[2*wv] = alt_l; sAlt[2*wv+1] = alt_r; }

    float mu_l = sum_l*(1.f/256.f), mu_r = sum_r*(1.f/256.f);
    float var_fl = fmaxf((sq_l - 256.f*mu_l*mu_l)*(1.f/255.f), 0.f);
    float var_fr = fmaxf((sq_r - 256.f*mu_r*mu_r)*(1.f/255.f), 0.f);
    float std_l = sqrtf(var_fl), std_r = sqrtf(var_fr);
    float inv_l = 1.f/fmaxf(std_l,1e-6f), inv_r = 1.f/fmaxf(std_r,1e-6f);

    float p3l_c=0.f, p4l_c=0.f, p3r_c=0.f, p4r_c=0.f;
    {
      float p,p2;
      p=(xl.x-mu_l)*inv_l; p2=p*p; p3l_c+=p2*p; p4l_c+=p2*p2;
      p=(xl.y-mu_l)*inv_l; p2=p*p; p3l_c+=p2*p; p4l_c+=p2*p2;
      p=(xl.z-mu_l)*inv_l; p2=p*p; p3l_c+=p2*p; p4l_c+=p2*p2;
      p=(xl.w-mu_l)*inv_l; p2=p*p; p3l_c+=p2*p; p4l_c+=p2*p2;
      p=(xr.x-mu_r)*inv_r; p2=p*p; p3r_c+=p2*p; p4r_c+=p2*p2;
      p=(xr.y-mu_r)*inv_r; p2=p*p; p3r_c+=p2*p; p4r_c+=p2*p2;
      p=(xr.z-mu_r)*inv_r; p2=p*p; p3r_c+=p2*p; p4r_c+=p2*p2;
      p=(xr.w-mu_r)*inv_r; p2=p*p; p3r_c+=p2*p; p4r_c+=p2*p2;
    }
    float p3l = wsum(p3l_c), p4l = wsum(p4l_c);
    float p3r = wsum(p3r_c), p4r = wsum(p4r_c);

    float thr_l = 0.3f*pk_l, thr_r = 0.3f*pk_r;
    float dl_c = (fabsf(xl.x)>=thr_l?1.f:0.f) + (fabsf(xl.y)>=thr_l?1.f:0.f)
               + (fabsf(xl.z)>=thr_l?1.f:0.f) + (fabsf(xl.w)>=thr_l?1.f:0.f);
    float dr_c = (fabsf(xr.x)>=thr_r?1.f:0.f) + (fabsf(xr.y)>=thr_r?1.f:0.f)
               + (fabsf(xr.z)>=thr_r?1.f:0.f) + (fabsf(xr.w)>=thr_r?1.f:0.f);
    float dur_l = wsum(dl_c), dur_r = wsum(dr_c);

    float nxl = __shfl_down(xl.x,1), nxr = __shfl_down(xr.x,1);
    float nyl = __shfl_down(yl.x,1), nyr = __shfl_down(yr.x,1);
    const bool lastl = (lane==63);
    float zl_c = ((xl.x<0.f)!=(xl.y<0.f)?1.f:0.f) + ((xl.y<0.f)!=(xl.z<0.f)?1.f:0.f)
               + ((xl.z<0.f)!=(xl.w<0.f)?1.f:0.f)
               + ((!lastl && ((xl.w<0.f)!=(nxl<0.f)))?1.f:0.f);
    float zr_c = ((xr.x<0.f)!=(xr.y<0.f)?1.f:0.f) + ((xr.y<0.f)!=(xr.z<0.f)?1.f:0.f)
               + ((xr.z<0.f)!=(xr.w<0.f)?1.f:0.f)
               + ((!lastl && ((xr.w<0.f)!=(nxr<0.f)))?1.f:0.f);
    float zc_l = wsum(zl_c), zc_r = wsum(zr_c);
    float vl_c = fabsf(yl.y-yl.x)+fabsf(yl.z-yl.y)+fabsf(yl.w-yl.z) + (lastl?0.f:fabsf(nyl-yl.w));
    float vr_c = fabsf(yr.y-yr.x)+fabsf(yr.z-yr.y)+fabsf(yr.w-yr.z) + (lastl?0.f:fabsf(nyr-yr.w));
    float vib_l = wsum(vl_c), vib_r = wsum(vr_c);

    // ---- 6 gyro groups, software-pipelined loads
    float gvar[6], gpk[6];
    #pragma unroll
    for (int g=0; g<6; ++g){
      float4 n0v, n1v, n2v;
      if (g < 5) {
        const float* nbse = ((g+1)<2)? fp : ((g+1)<4)? sp : tp;
        const float* nsrc = nbse + (((g+1)&1)? 2304 : 768);
        n0v = ((const float4*)nsrc      )[lane];
        n1v = ((const float4*)(nsrc+256))[lane];
        n2v = ((const float4*)(nsrc+512))[lane];
      }
      float s0 = wsum(sum4(gc0));
      float s1 = wsum(sum4(gc1));
      float s2 = wsum(sum4(gc2));
      float qt = wsum(dot4(gc0)+dot4(gc1)+dot4(gc2));
      gpk[g]   = wmax(fmaxf(amax4(gc0),fmaxf(amax4(gc1),amax4(gc2))));
      gvar[g]  = (qt - (s0*s0+s1*s1+s2*s2)*(1.f/256.f))*(1.f/255.f);
      if (g < 5) { gc0=n0v; gc1=n1v; gc2=n2v; }
    }

    float var_sl = fmaxf((ssq_l - ssum_l*ssum_l*(1.f/256.f))*(1.f/255.f), 0.f);
    float var_sr = fmaxf((ssq_r - ssum_r*ssum_r*(1.f/256.f))*(1.f/255.f), 0.f);
    float frms_l = sqrtf(sq_l *(1.f/256.f)), frms_r = sqrtf(sq_r *(1.f/256.f));
    float srms_l = sqrtf(ssq_l*(1.f/256.f)), srms_r = sqrtf(ssq_r*(1.f/256.f));
    float fgv_l = log1pf(gvar[0]), fgv_r = log1pf(gvar[1]);
    float sgv_l = log1pf(gvar[2]), sgv_r = log1pf(gvar[3]);
    float tgv_l = log1pf(gvar[4]), tgv_r = log1pf(gvar[5]);

    if (lane == 0) {
      float* o = out + (size_t)b*44;
      o[0]  = pk_l;  o[1]  = pk_r;
      o[2]  = spk_l; o[3]  = spk_r;
      o[4]  = log1pf(pk_l/(spk_l+1e-4f));
      o[5]  = log1pf(pk_r/(spk_r+1e-4f));
      o[8]  = std_l; o[9]  = std_r;
      o[10] = (h1l*(1.f/128.f))/(h2l*(1.f/128.f)+1e-6f);
      o[11] = (h1r*(1.f/128.f))/(h2r*(1.f/128.f)+1e-6f);
      o[12] = vib_l*(1.f/255.f);
      o[13] = vib_r*(1.f/255.f);
      o[14] = log1pf(var_fl/(var_sl+1e-4f));
      o[15] = log1pf(var_fr/(var_sr+1e-4f));
      o[18] = dur_l*(1.f/256.f);
      o[19] = dur_r*(1.f/256.f);
      o[20] = fgv_l; o[21] = fgv_r;
      o[22] = gpk[0]; o[23] = gpk[1];
      o[24] = sgv_l; o[25] = sgv_r;
      o[26] = gpk[2]; o[27] = gpk[3];
      o[28] = tgv_l; o[29] = tgv_r;
      o[30] = gpk[4]; o[31] = gpk[5];
      o[32] = fabsf(pk_l-spk_l);
      o[33] = fabsf(pk_r-spk_r);
      o[34] = fabsf(fgv_l-sgv_l);
      o[35] = fabsf(fgv_r-sgv_r);
      o[36] = log1pf(srms_l/(frms_l+1e-6f));
      o[37] = log1pf(srms_r/(frms_r+1e-6f));
      o[38] = clampf(p4l*(1.f/256.f), -10.f, 30.f);
      o[39] = clampf(p4r*(1.f/256.f), -10.f, 30.f);
      o[40] = clampf(p3l*(1.f/256.f), -10.f, 10.f);
      o[41] = clampf(p3r*(1.f/256.f), -10.f, 10.f);
      o[42] = zc_l*(1.f/255.f);
      o[43] = zc_r*(1.f/255.f);
    }
  }

  // ---- preload s=0 B fragments (independent of LDS), then barrier
  const int col = lane & 15;
  const int g   = lane >> 4;
  const int T   = wv;                       // wave = bin tile, bins 16T..16T+15
  const short8* ws8 = (const short8*)ws;
  short8 bc = ws8[((T*8+0)*2+0)*64 + lane];
  short8 bs = ws8[((T*8+0)*2+1)*64 + lane];
  __syncthreads();

  // ================= Phase 2: DFT via MFMA =================
  {
    f32x4 ac={0,0,0,0}, as={0,0,0,0};
    #pragma unroll
    for (int s=0; s<8; ++s){
      unsigned abyte = (((unsigned)col<<9) + ((unsigned)g<<4) + ((unsigned)s<<6))
                       ^ (((unsigned)(col&7))<<4);
      short8 af = *(const short8*)((const char*)sA + abyte);
      short8 bcn, bsn;
      if (s < 7) {
        bcn = ws8[((T*8+s+1)*2+0)*64 + lane];
        bsn = ws8[((T*8+s+1)*2+1)*64 + lane];
      }
      ac = __builtin_amdgcn_mfma_f32_16x16x32_bf16(af, bc, ac, 0,0,0);
      as = __builtin_amdgcn_mfma_f32_16x16x32_bf16(af, bs, as, 0,0,0);
      if (s < 7) { bc = bcn; bs = bsn; }
    }

    float kf = (float)(T*16 + col);
    #pragma unroll
    for (int q=0; q<4; ++q){
      int row = (g<<2) + q;
      float P = ac[q]*ac[q] + as[q]*as[q];
      float tp = red16(P);
      float cp = red16(kf*P);
      float hp;
      if (T == 3)      hp = red16(col >= 12 ? P : 0.f);   // bins 48..63: keep >=60
      else if (T >= 4) hp = tp;
      else             hp = 0.f;
      if (col == 0) {
        sPart[T][row][0]=tp; sPart[T][row][1]=hp; sPart[T][row][2]=cp;
      }
    }
  }
  __syncthreads();

  // ================= Phase 3: combine spectral partials =================
  if (t < 16) {
    const int row = t;
    const long long bb = (long long)blockIdx.x*8 + (row>>1);
    if (bb < B) {
      float tot=0.f, hp=0.f, cw=0.f;
      #pragma unroll
      for (int tl=0; tl<8; ++tl){
        tot += sPart[tl][row][0];
        hp  += sPart[tl][row][1];
        cw  += sPart[tl][row][2];
      }
      float a = sAlt[row], P128 = a*a;
      tot += P128; hp += P128; cw = fmaf(128.f, P128, cw);
      int ch = row & 1;
      float* o = out + (size_t)bb*44;
      o[6+ch]  = hp/(tot+1e-6f);
      o[16+ch] = cw/(tot+1e-6f)*(1.f/129.f);
    }
  }
}

extern "C" void kernel_launch(void* const* d_in, const int* in_sizes, int n_in,
                              void* d_out, int out_size, void* d_ws, size_t ws_size,
                              hipStream_t stream) {
  const float* foot  = (const float*)d_in[0];
  const float* shank = (const float*)d_in[1];
  const float* thigh = (const float*)d_in[2];
  float* out = (float*)d_out;
  unsigned short* ws = (unsigned short*)d_ws;
  int B = in_sizes[0] / (12 * 256);
  build_trig<<<dim3(32), dim3(256), 0, stream>>>(ws);
  biomech_kernel<<<dim3((B+7)/8), dim3(512), 0, stream>>>(foot, shank, thigh, ws, out, B);
}

// Round 6
// 53.832 us; speedup vs baseline: 1.2117x; 1.2117x over previous
//
#include <hip/hip_runtime.h>
#include <math.h>

// BioMechFeatures: B x 12 x 256 f32 (foot, shank, thigh) -> B x 44 f32.
// Kernel 1 (build_trig): precompute DFT B-matrix bf16 MFMA fragments -> d_ws (128 KB).
// Kernel 2 (biomech): block = 512 threads (8 waves) = 8 batches, 1 batch/wave.
//   All reductions via VALU DPP (row_shr/row_bcast), NOT ds_swizzle — short latency chains.
//   Phase 2: DFT power via mfma_f32_16x16x32_bf16; B fragments streamed from d_ws (L2-hot).

typedef __attribute__((ext_vector_type(8))) short short8;
typedef __attribute__((ext_vector_type(4))) float f32x4;

__device__ __forceinline__ float bcast63(float v){
  return __int_as_float(__builtin_amdgcn_readlane(__float_as_int(v), 63));
}
// full wave-64 sum -> broadcast (6 DPP VALU ops + readlane)
__device__ __forceinline__ float wsum(float v){
  v += __int_as_float(__builtin_amdgcn_update_dpp(0, __float_as_int(v), 0x111, 0xF, 0xF, true)); // row_shr:1
  v += __int_as_float(__builtin_amdgcn_update_dpp(0, __float_as_int(v), 0x112, 0xF, 0xF, true)); // row_shr:2
  v += __int_as_float(__builtin_amdgcn_update_dpp(0, __float_as_int(v), 0x114, 0xF, 0xF, true)); // row_shr:4
  v += __int_as_float(__builtin_amdgcn_update_dpp(0, __float_as_int(v), 0x118, 0xF, 0xF, true)); // row_shr:8
  v += __int_as_float(__builtin_amdgcn_update_dpp(0, __float_as_int(v), 0x142, 0xF, 0xF, true)); // row_bcast:15
  v += __int_as_float(__builtin_amdgcn_update_dpp(0, __float_as_int(v), 0x143, 0xF, 0xF, true)); // row_bcast:31
  return bcast63(v);
}
// full wave-64 max of NON-NEGATIVE values (bound_ctrl zero-fill is identity)
__device__ __forceinline__ float wmax(float v){
  v = fmaxf(v, __int_as_float(__builtin_amdgcn_update_dpp(0, __float_as_int(v), 0x111, 0xF, 0xF, true)));
  v = fmaxf(v, __int_as_float(__builtin_amdgcn_update_dpp(0, __float_as_int(v), 0x112, 0xF, 0xF, true)));
  v = fmaxf(v, __int_as_float(__builtin_amdgcn_update_dpp(0, __float_as_int(v), 0x114, 0xF, 0xF, true)));
  v = fmaxf(v, __int_as_float(__builtin_amdgcn_update_dpp(0, __float_as_int(v), 0x118, 0xF, 0xF, true)));
  v = fmaxf(v, __int_as_float(__builtin_amdgcn_update_dpp(0, __float_as_int(v), 0x142, 0xF, 0xF, true)));
  v = fmaxf(v, __int_as_float(__builtin_amdgcn_update_dpp(0, __float_as_int(v), 0x143, 0xF, 0xF, true)));
  return bcast63(v);
}
// sum within each 16-lane row; result valid in lane (16r+15)
__device__ __forceinline__ float red16hi(float v){
  v += __int_as_float(__builtin_amdgcn_update_dpp(0, __float_as_int(v), 0x111, 0xF, 0xF, true));
  v += __int_as_float(__builtin_amdgcn_update_dpp(0, __float_as_int(v), 0x112, 0xF, 0xF, true));
  v += __int_as_float(__builtin_amdgcn_update_dpp(0, __float_as_int(v), 0x114, 0xF, 0xF, true));
  v += __int_as_float(__builtin_amdgcn_update_dpp(0, __float_as_int(v), 0x118, 0xF, 0xF, true));
  return v;
}
__device__ __forceinline__ float sum4(float4 v){ return (v.x+v.y)+(v.z+v.w); }
__device__ __forceinline__ float dot4(float4 v){ return (v.x*v.x+v.y*v.y)+(v.z*v.z+v.w*v.w); }
__device__ __forceinline__ float amax4(float4 v){ return fmaxf(fmaxf(fabsf(v.x),fabsf(v.y)),fmaxf(fabsf(v.z),fabsf(v.w))); }
__device__ __forceinline__ float asum4(float4 v){ return (fabsf(v.x)+fabsf(v.y))+(fabsf(v.z)+fabsf(v.w)); }
__device__ __forceinline__ float clampf(float v,float lo,float hi){ return fminf(fmaxf(v,lo),hi); }
__device__ __forceinline__ unsigned short f2bf(float f){   // RNE f32->bf16
  unsigned u = __float_as_uint(f);
  return (unsigned short)((u + 0x7FFFu + ((u>>16)&1u)) >> 16);
}

// ---------- B-fragment precompute: 8 tiles x 8 s x {cos,sin} x 64 lanes x 8 bf16 ----------
__global__ __launch_bounds__(256) void build_trig(unsigned short* __restrict__ ws){
  int id   = blockIdx.x*256 + threadIdx.x;   // 0..8191
  int lane = id & 63;
  int f    = (id>>6) & 1;                    // 0=cos, 1=sin
  int s    = (id>>7) & 7;
  int T    = (id>>10) & 7;                   // bin tile
  int nb   = T*16 + (lane&15);               // bin
  int n0   = ((lane>>4)<<3) + (s<<5);        // sample base
  short8 v;
  #pragma unroll
  for (int j=0;j<8;++j){
    int m = ((n0+j)*nb) & 255;
    if (f) m = (m+192)&255;                  // sin(x) = cos(x - pi/2)
    v[j] = (short)f2bf(__cosf((float)m * 0.0245436926066f));
  }
  *(short8*)(ws + (size_t)id*8) = v;
}

__global__ __launch_bounds__(512,4) void biomech_kernel(
    const float* __restrict__ foot, const float* __restrict__ shank,
    const float* __restrict__ thigh, const unsigned short* __restrict__ ws,
    float* __restrict__ out, int B)
{
  const int t    = threadIdx.x;
  const int lane = t & 63;
  const int wv   = t >> 6;                 // 0..7

  __shared__ __align__(16) unsigned short sA[16*256];  // 8KB bf16 A, XOR-swizzled
  __shared__ float sPart[8][16][3];
  __shared__ float sAlt[16];

  const long long b = (long long)blockIdx.x*8 + wv;
  if (b < B) {
    const float* fp = foot  + (size_t)b*3072;
    const float* sp = shank + (size_t)b*3072;
    const float* tp = thigh + (size_t)b*3072;

    // ---- issue z loads + first gyro group early
    float4 xl = ((const float4*)(fp+ 512))[lane];
    float4 xr = ((const float4*)(fp+2048))[lane];
    float4 yl = ((const float4*)(sp+ 512))[lane];
    float4 yr = ((const float4*)(sp+2048))[lane];
    float4 gc0 = ((const float4*)(fp+ 768))[lane];
    float4 gc1 = ((const float4*)(fp+1024))[lane];
    float4 gc2 = ((const float4*)(fp+1280))[lane];

    // ---- stage foot-z rows bf16 into swizzled LDS (rows 2wv, 2wv+1)
    {
      int r0 = 2*wv, r1 = 2*wv+1;
      unsigned lo0 = (unsigned)f2bf(xl.x) | ((unsigned)f2bf(xl.y)<<16);
      unsigned hi0 = (unsigned)f2bf(xl.z) | ((unsigned)f2bf(xl.w)<<16);
      unsigned by0 = (((unsigned)r0<<9) + ((unsigned)lane<<3)) ^ (((unsigned)(r0&7))<<4);
      *(uint2*)((char*)sA + by0) = make_uint2(lo0,hi0);
      unsigned lo1 = (unsigned)f2bf(xr.x) | ((unsigned)f2bf(xr.y)<<16);
      unsigned hi1 = (unsigned)f2bf(xr.z) | ((unsigned)f2bf(xr.w)<<16);
      unsigned by1 = (((unsigned)r1<<9) + ((unsigned)lane<<3)) ^ (((unsigned)(r1&7))<<4);
      *(uint2*)((char*)sA + by1) = make_uint2(lo1,hi1);
    }

    // ---- z-channel reductions (all DPP)
    float pk_l  = wmax(amax4(xl)), pk_r  = wmax(amax4(xr));
    float spk_l = wmax(amax4(yl)), spk_r = wmax(amax4(yr));
    float sum_l = wsum(sum4(xl)),  sum_r = wsum(sum4(xr));
    float sq_l  = wsum(dot4(xl)),  sq_r  = wsum(dot4(xr));
    float ssum_l= wsum(sum4(yl)),  ssum_r= wsum(sum4(yr));
    float ssq_l = wsum(dot4(yl)),  ssq_r = wsum(dot4(yr));
    float al = asum4(xl), ar = asum4(xr);
    float h1l = wsum(lane<32 ? al : 0.f), h2l = wsum(lane<32 ? 0.f : al);
    float h1r = wsum(lane<32 ? ar : 0.f), h2r = wsum(lane<32 ? 0.f : ar);
    float alt_l = wsum((xl.x - xl.y) + (xl.z - xl.w));
    float alt_r = wsum((xr.x - xr.y) + (xr.z - xr.w));
    if (lane == 0) { sAlt[2*wv] = alt_l; sAlt[2*wv+1] = alt_r; }

    float mu_l = sum_l*(1.f/256.f), mu_r = sum_r*(1.f/256.f);
    float var_fl = fmaxf((sq_l - 256.f*mu_l*mu_l)*(1.f/255.f), 0.f);
    float var_fr = fmaxf((sq_r - 256.f*mu_r*mu_r)*(1.f/255.f), 0.f);
    float std_l = sqrtf(var_fl), std_r = sqrtf(var_fr);
    float inv_l = 1.f/fmaxf(std_l,1e-6f), inv_r = 1.f/fmaxf(std_r,1e-6f);

    float p3l_c=0.f, p4l_c=0.f, p3r_c=0.f, p4r_c=0.f;
    {
      float p,p2;
      p=(xl.x-mu_l)*inv_l; p2=p*p; p3l_c+=p2*p; p4l_c+=p2*p2;
      p=(xl.y-mu_l)*inv_l; p2=p*p; p3l_c+=p2*p; p4l_c+=p2*p2;
      p=(xl.z-mu_l)*inv_l; p2=p*p; p3l_c+=p2*p; p4l_c+=p2*p2;
      p=(xl.w-mu_l)*inv_l; p2=p*p; p3l_c+=p2*p; p4l_c+=p2*p2;
      p=(xr.x-mu_r)*inv_r; p2=p*p; p3r_c+=p2*p; p4r_c+=p2*p2;
      p=(xr.y-mu_r)*inv_r; p2=p*p; p3r_c+=p2*p; p4r_c+=p2*p2;
      p=(xr.z-mu_r)*inv_r; p2=p*p; p3r_c+=p2*p; p4r_c+=p2*p2;
      p=(xr.w-mu_r)*inv_r; p2=p*p; p3r_c+=p2*p; p4r_c+=p2*p2;
    }
    float p3l = wsum(p3l_c), p4l = wsum(p4l_c);
    float p3r = wsum(p3r_c), p4r = wsum(p4r_c);

    float thr_l = 0.3f*pk_l, thr_r = 0.3f*pk_r;
    float dl_c = (fabsf(xl.x)>=thr_l?1.f:0.f) + (fabsf(xl.y)>=thr_l?1.f:0.f)
               + (fabsf(xl.z)>=thr_l?1.f:0.f) + (fabsf(xl.w)>=thr_l?1.f:0.f);
    float dr_c = (fabsf(xr.x)>=thr_r?1.f:0.f) + (fabsf(xr.y)>=thr_r?1.f:0.f)
               + (fabsf(xr.z)>=thr_r?1.f:0.f) + (fabsf(xr.w)>=thr_r?1.f:0.f);
    float dur_l = wsum(dl_c), dur_r = wsum(dr_c);

    float nxl = __shfl_down(xl.x,1), nxr = __shfl_down(xr.x,1);
    float nyl = __shfl_down(yl.x,1), nyr = __shfl_down(yr.x,1);
    const bool lastl = (lane==63);
    float zl_c = ((xl.x<0.f)!=(xl.y<0.f)?1.f:0.f) + ((xl.y<0.f)!=(xl.z<0.f)?1.f:0.f)
               + ((xl.z<0.f)!=(xl.w<0.f)?1.f:0.f)
               + ((!lastl && ((xl.w<0.f)!=(nxl<0.f)))?1.f:0.f);
    float zr_c = ((xr.x<0.f)!=(xr.y<0.f)?1.f:0.f) + ((xr.y<0.f)!=(xr.z<0.f)?1.f:0.f)
               + ((xr.z<0.f)!=(xr.w<0.f)?1.f:0.f)
               + ((!lastl && ((xr.w<0.f)!=(nxr<0.f)))?1.f:0.f);
    float zc_l = wsum(zl_c), zc_r = wsum(zr_c);
    float vl_c = fabsf(yl.y-yl.x)+fabsf(yl.z-yl.y)+fabsf(yl.w-yl.z) + (lastl?0.f:fabsf(nyl-yl.w));
    float vr_c = fabsf(yr.y-yr.x)+fabsf(yr.z-yr.y)+fabsf(yr.w-yr.z) + (lastl?0.f:fabsf(nyr-yr.w));
    float vib_l = wsum(vl_c), vib_r = wsum(vr_c);

    // ---- 6 gyro groups, software-pipelined loads
    float gvar[6], gpk[6];
    #pragma unroll
    for (int g=0; g<6; ++g){
      float4 n0v, n1v, n2v;
      if (g < 5) {
        const float* nbse = ((g+1)<2)? fp : ((g+1)<4)? sp : tp;
        const float* nsrc = nbse + (((g+1)&1)? 2304 : 768);
        n0v = ((const float4*)nsrc      )[lane];
        n1v = ((const float4*)(nsrc+256))[lane];
        n2v = ((const float4*)(nsrc+512))[lane];
      }
      float s0 = wsum(sum4(gc0));
      float s1 = wsum(sum4(gc1));
      float s2 = wsum(sum4(gc2));
      float qt = wsum(dot4(gc0)+dot4(gc1)+dot4(gc2));
      gpk[g]   = wmax(fmaxf(amax4(gc0),fmaxf(amax4(gc1),amax4(gc2))));
      gvar[g]  = (qt - (s0*s0+s1*s1+s2*s2)*(1.f/256.f))*(1.f/255.f);
      if (g < 5) { gc0=n0v; gc1=n1v; gc2=n2v; }
    }

    float var_sl = fmaxf((ssq_l - ssum_l*ssum_l*(1.f/256.f))*(1.f/255.f), 0.f);
    float var_sr = fmaxf((ssq_r - ssum_r*ssum_r*(1.f/256.f))*(1.f/255.f), 0.f);
    float frms_l = sqrtf(sq_l *(1.f/256.f)), frms_r = sqrtf(sq_r *(1.f/256.f));
    float srms_l = sqrtf(ssq_l*(1.f/256.f)), srms_r = sqrtf(ssq_r*(1.f/256.f));
    float fgv_l = log1pf(gvar[0]), fgv_r = log1pf(gvar[1]);
    float sgv_l = log1pf(gvar[2]), sgv_r = log1pf(gvar[3]);
    float tgv_l = log1pf(gvar[4]), tgv_r = log1pf(gvar[5]);

    if (lane == 0) {
      float* o = out + (size_t)b*44;
      float4 v0 = {pk_l, pk_r, spk_l, spk_r};
      float2 v4 = {log1pf(pk_l/(spk_l+1e-4f)), log1pf(pk_r/(spk_r+1e-4f))};
      float4 v8 = {std_l, std_r,
                   (h1l*(1.f/128.f))/(h2l*(1.f/128.f)+1e-6f),
                   (h1r*(1.f/128.f))/(h2r*(1.f/128.f)+1e-6f)};
      float4 v12 = {vib_l*(1.f/255.f), vib_r*(1.f/255.f),
                    log1pf(var_fl/(var_sl+1e-4f)), log1pf(var_fr/(var_sr+1e-4f))};
      float2 v18 = {dur_l*(1.f/256.f), dur_r*(1.f/256.f)};
      float4 v20 = {fgv_l, fgv_r, gpk[0], gpk[1]};
      float4 v24 = {sgv_l, sgv_r, gpk[2], gpk[3]};
      float4 v28 = {tgv_l, tgv_r, gpk[4], gpk[5]};
      float4 v32 = {fabsf(pk_l-spk_l), fabsf(pk_r-spk_r),
                    fabsf(fgv_l-sgv_l), fabsf(fgv_r-sgv_r)};
      float4 v36 = {log1pf(srms_l/(frms_l+1e-6f)), log1pf(srms_r/(frms_r+1e-6f)),
                    clampf(p4l*(1.f/256.f), -10.f, 30.f), clampf(p4r*(1.f/256.f), -10.f, 30.f)};
      float4 v40 = {clampf(p3l*(1.f/256.f), -10.f, 10.f), clampf(p3r*(1.f/256.f), -10.f, 10.f),
                    zc_l*(1.f/255.f), zc_r*(1.f/255.f)};
      *(float4*)(o+0)  = v0;  *(float2*)(o+4)  = v4;
      *(float4*)(o+8)  = v8;  *(float4*)(o+12) = v12;
      *(float2*)(o+18) = v18; *(float4*)(o+20) = v20;
      *(float4*)(o+24) = v24; *(float4*)(o+28) = v28;
      *(float4*)(o+32) = v32; *(float4*)(o+36) = v36;
      *(float4*)(o+40) = v40;
    }
  }

  // ---- preload s=0 B fragments (independent of LDS), then barrier
  const int col = lane & 15;
  const int g   = lane >> 4;
  const int T   = wv;                       // wave = bin tile, bins 16T..16T+15
  const short8* ws8 = (const short8*)ws;
  short8 bc = ws8[((T*8+0)*2+0)*64 + lane];
  short8 bs = ws8[((T*8+0)*2+1)*64 + lane];
  __syncthreads();

  // ================= Phase 2: DFT via MFMA =================
  {
    f32x4 ac={0,0,0,0}, as={0,0,0,0};
    #pragma unroll
    for (int s=0; s<8; ++s){
      unsigned abyte = (((unsigned)col<<9) + ((unsigned)g<<4) + ((unsigned)s<<6))
                       ^ (((unsigned)(col&7))<<4);
      short8 af = *(const short8*)((const char*)sA + abyte);
      short8 bcn, bsn;
      if (s < 7) {
        bcn = ws8[((T*8+s+1)*2+0)*64 + lane];
        bsn = ws8[((T*8+s+1)*2+1)*64 + lane];
      }
      ac = __builtin_amdgcn_mfma_f32_16x16x32_bf16(af, bc, ac, 0,0,0);
      as = __builtin_amdgcn_mfma_f32_16x16x32_bf16(af, bs, as, 0,0,0);
      if (s < 7) { bc = bcn; bs = bsn; }
    }

    float kf = (float)(T*16 + col);
    #pragma unroll
    for (int q=0; q<4; ++q){
      int row = (g<<2) + q;
      float P = ac[q]*ac[q] + as[q]*as[q];
      float tp = red16hi(P);
      float cp = red16hi(kf*P);
      float hp;
      if (T == 3)      hp = red16hi(col >= 12 ? P : 0.f);   // bins 48..63: keep >=60
      else if (T >= 4) hp = tp;
      else             hp = 0.f;
      if (col == 15) {   // row sums live in lane 15 of each 16-lane row
        sPart[T][row][0]=tp; sPart[T][row][1]=hp; sPart[T][row][2]=cp;
      }
    }
  }
  __syncthreads();

  // ================= Phase 3: combine spectral partials =================
  if (t < 16) {
    const int row = t;
    const long long bb = (long long)blockIdx.x*8 + (row>>1);
    if (bb < B) {
      float tot=0.f, hp=0.f, cw=0.f;
      #pragma unroll
      for (int tl=0; tl<8; ++tl){
        tot += sPart[tl][row][0];
        hp  += sPart[tl][row][1];
        cw  += sPart[tl][row][2];
      }
      float a = sAlt[row], P128 = a*a;
      tot += P128; hp += P128; cw = fmaf(128.f, P128, cw);
      int ch = row & 1;
      float* o = out + (size_t)bb*44;
      o[6+ch]  = hp/(tot+1e-6f);
      o[16+ch] = cw/(tot+1e-6f)*(1.f/129.f);
    }
  }
}

extern "C" void kernel_launch(void* const* d_in, const int* in_sizes, int n_in,
                              void* d_out, int out_size, void* d_ws, size_t ws_size,
                              hipStream_t stream) {
  const float* foot  = (const float*)d_in[0];
  const float* shank = (const float*)d_in[1];
  const float* thigh = (const float*)d_in[2];
  float* out = (float*)d_out;
  unsigned short* ws = (unsigned short*)d_ws;
  int B = in_sizes[0] / (12 * 256);
  build_trig<<<dim3(32), dim3(256), 0, stream>>>(ws);
  biomech_kernel<<<dim3((B+7)/8), dim3(512), 0, stream>>>(foot, shank, thigh, ws, out, B);
}

// Round 8
// 52.185 us; speedup vs baseline: 1.2500x; 1.0316x over previous
//
#include <hip/hip_runtime.h>
#include <math.h>

// BioMechFeatures: B x 12 x 256 f32 (foot, shank, thigh) -> B x 44 f32.
// Kernel 1 (build_trig): precompute DFT B-matrix bf16 MFMA fragments -> d_ws (128 KB).
// Kernel 2 (biomech): block = 512 threads (8 waves) = 8 batches, 1 batch/wave.
//   All reductions via VALU DPP (round-6 verified forms). All 22 float4 loads hoisted
//   (single latency exposure). DFT via mfma_f32_16x16x32_bf16, B pipelined depth-2.

typedef __attribute__((ext_vector_type(8))) short short8;
typedef __attribute__((ext_vector_type(4))) float f32x4;

__device__ __forceinline__ float bcast63(float v){
  return __int_as_float(__builtin_amdgcn_readlane(__float_as_int(v), 63));
}
// full wave-64 sum -> broadcast (6 DPP VALU ops + readlane)
__device__ __forceinline__ float wsum(float v){
  v += __int_as_float(__builtin_amdgcn_update_dpp(0, __float_as_int(v), 0x111, 0xF, 0xF, true)); // row_shr:1
  v += __int_as_float(__builtin_amdgcn_update_dpp(0, __float_as_int(v), 0x112, 0xF, 0xF, true)); // row_shr:2
  v += __int_as_float(__builtin_amdgcn_update_dpp(0, __float_as_int(v), 0x114, 0xF, 0xF, true)); // row_shr:4
  v += __int_as_float(__builtin_amdgcn_update_dpp(0, __float_as_int(v), 0x118, 0xF, 0xF, true)); // row_shr:8
  v += __int_as_float(__builtin_amdgcn_update_dpp(0, __float_as_int(v), 0x142, 0xF, 0xF, true)); // row_bcast:15
  v += __int_as_float(__builtin_amdgcn_update_dpp(0, __float_as_int(v), 0x143, 0xF, 0xF, true)); // row_bcast:31
  return bcast63(v);
}
// full wave-64 max of NON-NEGATIVE values (bound_ctrl zero-fill is identity)
__device__ __forceinline__ float wmax(float v){
  v = fmaxf(v, __int_as_float(__builtin_amdgcn_update_dpp(0, __float_as_int(v), 0x111, 0xF, 0xF, true)));
  v = fmaxf(v, __int_as_float(__builtin_amdgcn_update_dpp(0, __float_as_int(v), 0x112, 0xF, 0xF, true)));
  v = fmaxf(v, __int_as_float(__builtin_amdgcn_update_dpp(0, __float_as_int(v), 0x114, 0xF, 0xF, true)));
  v = fmaxf(v, __int_as_float(__builtin_amdgcn_update_dpp(0, __float_as_int(v), 0x118, 0xF, 0xF, true)));
  v = fmaxf(v, __int_as_float(__builtin_amdgcn_update_dpp(0, __float_as_int(v), 0x142, 0xF, 0xF, true)));
  v = fmaxf(v, __int_as_float(__builtin_amdgcn_update_dpp(0, __float_as_int(v), 0x143, 0xF, 0xF, true)));
  return bcast63(v);
}
// sum within each 16-lane row; result valid in lane (16r+15)
__device__ __forceinline__ float red16hi(float v){
  v += __int_as_float(__builtin_amdgcn_update_dpp(0, __float_as_int(v), 0x111, 0xF, 0xF, true));
  v += __int_as_float(__builtin_amdgcn_update_dpp(0, __float_as_int(v), 0x112, 0xF, 0xF, true));
  v += __int_as_float(__builtin_amdgcn_update_dpp(0, __float_as_int(v), 0x114, 0xF, 0xF, true));
  v += __int_as_float(__builtin_amdgcn_update_dpp(0, __float_as_int(v), 0x118, 0xF, 0xF, true));
  return v;
}
__device__ __forceinline__ float sum4(float4 v){ return (v.x+v.y)+(v.z+v.w); }
__device__ __forceinline__ float dot4(float4 v){ return (v.x*v.x+v.y*v.y)+(v.z*v.z+v.w*v.w); }
__device__ __forceinline__ float amax4(float4 v){ return fmaxf(fmaxf(fabsf(v.x),fabsf(v.y)),fmaxf(fabsf(v.z),fabsf(v.w))); }
__device__ __forceinline__ float asum4(float4 v){ return (fabsf(v.x)+fabsf(v.y))+(fabsf(v.z)+fabsf(v.w)); }
__device__ __forceinline__ float clampf(float v,float lo,float hi){ return fminf(fmaxf(v,lo),hi); }
__device__ __forceinline__ unsigned short f2bf(float f){   // RNE f32->bf16
  unsigned u = __float_as_uint(f);
  return (unsigned short)((u + 0x7FFFu + ((u>>16)&1u)) >> 16);
}

// ---------- B-fragment precompute: 8 tiles x 8 s x {cos,sin} x 64 lanes x 8 bf16 ----------
__global__ __launch_bounds__(256) void build_trig(unsigned short* __restrict__ ws){
  int id   = blockIdx.x*256 + threadIdx.x;   // 0..8191
  int lane = id & 63;
  int f    = (id>>6) & 1;                    // 0=cos, 1=sin
  int s    = (id>>7) & 7;
  int T    = (id>>10) & 7;                   // bin tile
  int nb   = T*16 + (lane&15);               // bin
  int n0   = ((lane>>4)<<3) + (s<<5);        // sample base
  short8 v;
  #pragma unroll
  for (int j=0;j<8;++j){
    int m = ((n0+j)*nb) & 255;
    if (f) m = (m+192)&255;                  // sin(x) = cos(x - pi/2)
    v[j] = (short)f2bf(__cosf((float)m * 0.0245436926066f));
  }
  *(short8*)(ws + (size_t)id*8) = v;
}

__global__ __launch_bounds__(512,4) void biomech_kernel(
    const float* __restrict__ foot, const float* __restrict__ shank,
    const float* __restrict__ thigh, const unsigned short* __restrict__ ws,
    float* __restrict__ out, int B)
{
  const int t    = threadIdx.x;
  const int lane = t & 63;
  const int wv   = t >> 6;                 // 0..7

  __shared__ __align__(16) unsigned short sA[16*256];  // 8KB bf16 A, XOR-swizzled
  __shared__ float sPart[8][16][3];
  __shared__ float sAlt[16];

  const long long b = (long long)blockIdx.x*8 + wv;
  if (b < B) {
    const float* fp = foot  + (size_t)b*3072;
    const float* sp = shank + (size_t)b*3072;
    const float* tp = thigh + (size_t)b*3072;

    // ================== hoist ALL loads (22 x float4) ==================
    float4 xl = ((const float4*)(fp+ 512))[lane];
    float4 xr = ((const float4*)(fp+2048))[lane];
    float4 yl = ((const float4*)(sp+ 512))[lane];
    float4 yr = ((const float4*)(sp+2048))[lane];
    float4 gv[6][3];
    #pragma unroll
    for (int g=0; g<6; ++g){
      const float* bse = (g<2)? fp : (g<4)? sp : tp;
      const float* src = bse + ((g&1)? 2304 : 768);
      gv[g][0] = ((const float4*)src      )[lane];
      gv[g][1] = ((const float4*)(src+256))[lane];
      gv[g][2] = ((const float4*)(src+512))[lane];
    }

    // ---- stage foot-z rows bf16 into swizzled LDS (rows 2wv, 2wv+1)
    {
      int r0 = 2*wv, r1 = 2*wv+1;
      unsigned lo0 = (unsigned)f2bf(xl.x) | ((unsigned)f2bf(xl.y)<<16);
      unsigned hi0 = (unsigned)f2bf(xl.z) | ((unsigned)f2bf(xl.w)<<16);
      unsigned by0 = (((unsigned)r0<<9) + ((unsigned)lane<<3)) ^ (((unsigned)(r0&7))<<4);
      *(uint2*)((char*)sA + by0) = make_uint2(lo0,hi0);
      unsigned lo1 = (unsigned)f2bf(xr.x) | ((unsigned)f2bf(xr.y)<<16);
      unsigned hi1 = (unsigned)f2bf(xr.z) | ((unsigned)f2bf(xr.w)<<16);
      unsigned by1 = (((unsigned)r1<<9) + ((unsigned)lane<<3)) ^ (((unsigned)(r1&7))<<4);
      *(uint2*)((char*)sA + by1) = make_uint2(lo1,hi1);
    }

    // ---- z-channel reductions (all DPP, round-6 forms)
    float pk_l  = wmax(amax4(xl)), pk_r  = wmax(amax4(xr));
    float spk_l = wmax(amax4(yl)), spk_r = wmax(amax4(yr));
    float sum_l = wsum(sum4(xl)),  sum_r = wsum(sum4(xr));
    float sq_l  = wsum(dot4(xl)),  sq_r  = wsum(dot4(xr));
    float ssum_l= wsum(sum4(yl)),  ssum_r= wsum(sum4(yr));
    float ssq_l = wsum(dot4(yl)),  ssq_r = wsum(dot4(yr));
    float al = asum4(xl), ar = asum4(xr);
    float h1l = wsum(lane<32 ? al : 0.f), h2l = wsum(lane<32 ? 0.f : al);
    float h1r = wsum(lane<32 ? ar : 0.f), h2r = wsum(lane<32 ? 0.f : ar);
    float alt_l = wsum((xl.x - xl.y) + (xl.z - xl.w));
    float alt_r = wsum((xr.x - xr.y) + (xr.z - xr.w));
    if (lane == 0) { sAlt[2*wv] = alt_l; sAlt[2*wv+1] = alt_r; }

    float mu_l = sum_l*(1.f/256.f), mu_r = sum_r*(1.f/256.f);
    float var_fl = fmaxf((sq_l - 256.f*mu_l*mu_l)*(1.f/255.f), 0.f);
    float var_fr = fmaxf((sq_r - 256.f*mu_r*mu_r)*(1.f/255.f), 0.f);
    float std_l = sqrtf(var_fl), std_r = sqrtf(var_fr);
    float inv_l = 1.f/fmaxf(std_l,1e-6f), inv_r = 1.f/fmaxf(std_r,1e-6f);

    float p3l_c=0.f, p4l_c=0.f, p3r_c=0.f, p4r_c=0.f;
    {
      float p,p2;
      p=(xl.x-mu_l)*inv_l; p2=p*p; p3l_c+=p2*p; p4l_c+=p2*p2;
      p=(xl.y-mu_l)*inv_l; p2=p*p; p3l_c+=p2*p; p4l_c+=p2*p2;
      p=(xl.z-mu_l)*inv_l; p2=p*p; p3l_c+=p2*p; p4l_c+=p2*p2;
      p=(xl.w-mu_l)*inv_l; p2=p*p; p3l_c+=p2*p; p4l_c+=p2*p2;
      p=(xr.x-mu_r)*inv_r; p2=p*p; p3r_c+=p2*p; p4r_c+=p2*p2;
      p=(xr.y-mu_r)*inv_r; p2=p*p; p3r_c+=p2*p; p4r_c+=p2*p2;
      p=(xr.z-mu_r)*inv_r; p2=p*p; p3r_c+=p2*p; p4r_c+=p2*p2;
      p=(xr.w-mu_r)*inv_r; p2=p*p; p3r_c+=p2*p; p4r_c+=p2*p2;
    }
    float p3l = wsum(p3l_c), p4l = wsum(p4l_c);
    float p3r = wsum(p3r_c), p4r = wsum(p4r_c);

    float thr_l = 0.3f*pk_l, thr_r = 0.3f*pk_r;
    float dl_c = (fabsf(xl.x)>=thr_l?1.f:0.f) + (fabsf(xl.y)>=thr_l?1.f:0.f)
               + (fabsf(xl.z)>=thr_l?1.f:0.f) + (fabsf(xl.w)>=thr_l?1.f:0.f);
    float dr_c = (fabsf(xr.x)>=thr_r?1.f:0.f) + (fabsf(xr.y)>=thr_r?1.f:0.f)
               + (fabsf(xr.z)>=thr_r?1.f:0.f) + (fabsf(xr.w)>=thr_r?1.f:0.f);
    float dur_l = wsum(dl_c), dur_r = wsum(dr_c);

    float nxl = __shfl_down(xl.x,1), nxr = __shfl_down(xr.x,1);
    float nyl = __shfl_down(yl.x,1), nyr = __shfl_down(yr.x,1);
    const bool lastl = (lane==63);
    float zl_c = ((xl.x<0.f)!=(xl.y<0.f)?1.f:0.f) + ((xl.y<0.f)!=(xl.z<0.f)?1.f:0.f)
               + ((xl.z<0.f)!=(xl.w<0.f)?1.f:0.f)
               + ((!lastl && ((xl.w<0.f)!=(nxl<0.f)))?1.f:0.f);
    float zr_c = ((xr.x<0.f)!=(xr.y<0.f)?1.f:0.f) + ((xr.y<0.f)!=(xr.z<0.f)?1.f:0.f)
               + ((xr.z<0.f)!=(xr.w<0.f)?1.f:0.f)
               + ((!lastl && ((xr.w<0.f)!=(nxr<0.f)))?1.f:0.f);
    float zc_l = wsum(zl_c), zc_r = wsum(zr_c);
    float vl_c = fabsf(yl.y-yl.x)+fabsf(yl.z-yl.y)+fabsf(yl.w-yl.z) + (lastl?0.f:fabsf(nyl-yl.w));
    float vr_c = fabsf(yr.y-yr.x)+fabsf(yr.z-yr.y)+fabsf(yr.w-yr.z) + (lastl?0.f:fabsf(nyr-yr.w));
    float vib_l = wsum(vl_c), vib_r = wsum(vr_c);

    // ---- 6 gyro groups (data already in registers)
    float gvar[6], gpk[6];
    #pragma unroll
    for (int g=0; g<6; ++g){
      float s0 = wsum(sum4(gv[g][0]));
      float s1 = wsum(sum4(gv[g][1]));
      float s2 = wsum(sum4(gv[g][2]));
      float qt = wsum(dot4(gv[g][0])+dot4(gv[g][1])+dot4(gv[g][2]));
      gpk[g]   = wmax(fmaxf(amax4(gv[g][0]),fmaxf(amax4(gv[g][1]),amax4(gv[g][2]))));
      gvar[g]  = (qt - (s0*s0+s1*s1+s2*s2)*(1.f/256.f))*(1.f/255.f);
    }

    float var_sl = fmaxf((ssq_l - ssum_l*ssum_l*(1.f/256.f))*(1.f/255.f), 0.f);
    float var_sr = fmaxf((ssq_r - ssum_r*ssum_r*(1.f/256.f))*(1.f/255.f), 0.f);
    float frms_l = sqrtf(sq_l *(1.f/256.f)), frms_r = sqrtf(sq_r *(1.f/256.f));
    float srms_l = sqrtf(ssq_l*(1.f/256.f)), srms_r = sqrtf(ssq_r*(1.f/256.f));
    float fgv_l = log1pf(gvar[0]), fgv_r = log1pf(gvar[1]);
    float sgv_l = log1pf(gvar[2]), sgv_r = log1pf(gvar[3]);
    float tgv_l = log1pf(gvar[4]), tgv_r = log1pf(gvar[5]);

    if (lane == 0) {
      float* o = out + (size_t)b*44;
      float4 v0 = {pk_l, pk_r, spk_l, spk_r};
      float2 v4 = {log1pf(pk_l/(spk_l+1e-4f)), log1pf(pk_r/(spk_r+1e-4f))};
      float4 v8 = {std_l, std_r,
                   (h1l*(1.f/128.f))/(h2l*(1.f/128.f)+1e-6f),
                   (h1r*(1.f/128.f))/(h2r*(1.f/128.f)+1e-6f)};
      float4 v12 = {vib_l*(1.f/255.f), vib_r*(1.f/255.f),
                    log1pf(var_fl/(var_sl+1e-4f)), log1pf(var_fr/(var_sr+1e-4f))};
      float2 v18 = {dur_l*(1.f/256.f), dur_r*(1.f/256.f)};
      float4 v20 = {fgv_l, fgv_r, gpk[0], gpk[1]};
      float4 v24 = {sgv_l, sgv_r, gpk[2], gpk[3]};
      float4 v28 = {tgv_l, tgv_r, gpk[4], gpk[5]};
      float4 v32 = {fabsf(pk_l-spk_l), fabsf(pk_r-spk_r),
                    fabsf(fgv_l-sgv_l), fabsf(fgv_r-sgv_r)};
      float4 v36 = {log1pf(srms_l/(frms_l+1e-6f)), log1pf(srms_r/(frms_r+1e-6f)),
                    clampf(p4l*(1.f/256.f), -10.f, 30.f), clampf(p4r*(1.f/256.f), -10.f, 30.f)};
      float4 v40 = {clampf(p3l*(1.f/256.f), -10.f, 10.f), clampf(p3r*(1.f/256.f), -10.f, 10.f),
                    zc_l*(1.f/255.f), zc_r*(1.f/255.f)};
      *(float4*)(o+0)  = v0;  *(float2*)(o+4)  = v4;
      *(float4*)(o+8)  = v8;  *(float4*)(o+12) = v12;
      *(float2*)(o+18) = v18; *(float4*)(o+20) = v20;
      *(float4*)(o+24) = v24; *(float4*)(o+28) = v28;
      *(float4*)(o+32) = v32; *(float4*)(o+36) = v36;
      *(float4*)(o+40) = v40;
    }
  }

  // ---- preload s=0,1 B fragments (independent of LDS), then barrier
  const int col = lane & 15;
  const int g16 = lane >> 4;
  const int T   = wv;                       // wave = bin tile, bins 16T..16T+15
  const short8* ws8 = (const short8*)ws;
  short8 bc0 = ws8[((T*8+0)*2+0)*64 + lane];
  short8 bs0 = ws8[((T*8+0)*2+1)*64 + lane];
  short8 bc1 = ws8[((T*8+1)*2+0)*64 + lane];
  short8 bs1 = ws8[((T*8+1)*2+1)*64 + lane];
  __syncthreads();

  // ================= Phase 2: DFT via MFMA (B pipelined depth-2) =================
  {
    f32x4 ac={0,0,0,0}, as={0,0,0,0};
    #pragma unroll
    for (int s=0; s<8; ++s){
      unsigned abyte = (((unsigned)col<<9) + ((unsigned)g16<<4) + ((unsigned)s<<6))
                       ^ (((unsigned)(col&7))<<4);
      short8 af = *(const short8*)((const char*)sA + abyte);
      short8 bcn, bsn;
      if (s < 6) {
        bcn = ws8[((T*8+s+2)*2+0)*64 + lane];
        bsn = ws8[((T*8+s+2)*2+1)*64 + lane];
      }
      ac = __builtin_amdgcn_mfma_f32_16x16x32_bf16(af, bc0, ac, 0,0,0);
      as = __builtin_amdgcn_mfma_f32_16x16x32_bf16(af, bs0, as, 0,0,0);
      bc0 = bc1; bs0 = bs1;
      if (s < 6) { bc1 = bcn; bs1 = bsn; }
    }

    float kf = (float)(T*16 + col);
    #pragma unroll
    for (int q=0; q<4; ++q){
      int row = (g16<<2) + q;
      float P = ac[q]*ac[q] + as[q]*as[q];
      float tp = red16hi(P);
      float cp = red16hi(kf*P);
      float hp;
      if (T == 3)      hp = red16hi(col >= 12 ? P : 0.f);   // bins 48..63: keep >=60
      else if (T >= 4) hp = tp;
      else             hp = 0.f;
      if (col == 15) {   // row sums live in lane 15 of each 16-lane row
        sPart[T][row][0]=tp; sPart[T][row][1]=hp; sPart[T][row][2]=cp;
      }
    }
  }
  __syncthreads();

  // ================= Phase 3: combine spectral partials =================
  if (t < 16) {
    const int row = t;
    const long long bb = (long long)blockIdx.x*8 + (row>>1);
    if (bb < B) {
      float tot=0.f, hp=0.f, cw=0.f;
      #pragma unroll
      for (int tl=0; tl<8; ++tl){
        tot += sPart[tl][row][0];
        hp  += sPart[tl][row][1];
        cw  += sPart[tl][row][2];
      }
      float a = sAlt[row], P128 = a*a;
      tot += P128; hp += P128; cw = fmaf(128.f, P128, cw);
      int ch = row & 1;
      float* o = out + (size_t)bb*44;
      o[6+ch]  = hp/(tot+1e-6f);
      o[16+ch] = cw/(tot+1e-6f)*(1.f/129.f);
    }
  }
}

extern "C" void kernel_launch(void* const* d_in, const int* in_sizes, int n_in,
                              void* d_out, int out_size, void* d_ws, size_t ws_size,
                              hipStream_t stream) {
  const float* foot  = (const float*)d_in[0];
  const float* shank = (const float*)d_in[1];
  const float* thigh = (const float*)d_in[2];
  float* out = (float*)d_out;
  unsigned short* ws = (unsigned short*)d_ws;
  int B = in_sizes[0] / (12 * 256);
  build_trig<<<dim3(32), dim3(256), 0, stream>>>(ws);
  biomech_kernel<<<dim3((B+7)/8), dim3(512), 0, stream>>>(foot, shank, thigh, ws, out, B);
}